// Round 1
// baseline (424.124 us; speedup 1.0000x reference)
//
#include <hip/hip_runtime.h>
#include <hip/hip_bf16.h>

#define NH    16
#define NKVH  4
#define HD    128
#define WIN   1024
#define SEQ   2048
#define QSCALE 0.08838834764831845f

typedef __attribute__((ext_vector_type(8))) short short8;
typedef __attribute__((ext_vector_type(4))) float float4v;

__device__ __forceinline__ unsigned short f2bf(float f) {
    unsigned int u = __float_as_uint(f);
    unsigned int r = (u + 0x7FFFu + ((u >> 16) & 1u)) >> 16;
    return (unsigned short)r;
}

// block = 256 threads = 4 waves; wave w handles head kvh*4+w, 32 queries (2 MFMA row-tiles)
// grid = B * NKVH * (SEQ/32)
__global__ __launch_bounds__(256, 2)
void attn_swa_sink_kernel(const float* __restrict__ qg, const float* __restrict__ kg,
                          const float* __restrict__ vg, const float* __restrict__ sinks,
                          float* __restrict__ og) {
    // LDS: K tile [32 keys][136 pad] bf16; V^T tile [128 dims][40 pad] bf16;
    // P per-wave [32 rows][40 pad] bf16
    __shared__ __align__(16) unsigned short Klds[32 * 136];
    __shared__ __align__(16) unsigned short Vlds[128 * 40];
    __shared__ __align__(16) unsigned short Plds[4][32 * 40];

    const int gid = blockIdx.x;
    const int qt  = gid & 63;          // q-tile within sequence
    const int bk  = gid >> 6;          // 0..15
    const int b   = bk >> 2;
    const int kvh = bk & 3;
    const int tid  = threadIdx.x;
    const int wave = tid >> 6;
    const int lane = tid & 63;
    const int l15  = lane & 15;
    const int quad = lane >> 4;        // 0..3
    const int h    = kvh * 4 + wave;
    const int q0   = qt * 32;

    const float* qbase = qg + (size_t)(b * SEQ) * (NH * HD);
    const float* kbase = kg + (size_t)(b * SEQ) * (NKVH * HD);
    const float* vbase = vg + (size_t)(b * SEQ) * (NKVH * HD);

    // ---- load Q fragments (A-layout: row = l15, k = quad*8+j), fp32 -> bf16 ----
    short8 qf[2][4];
    for (int qs = 0; qs < 2; ++qs) {
        const int row = q0 + qs * 16 + l15;
        const float* qr = qbase + (size_t)row * (NH * HD) + h * HD + quad * 8;
        for (int c = 0; c < 4; ++c) {
            float4 a = *(const float4*)(qr + c * 32);
            float4 bb = *(const float4*)(qr + c * 32 + 4);
            short8 f;
            f[0] = (short)f2bf(a.x);  f[1] = (short)f2bf(a.y);
            f[2] = (short)f2bf(a.z);  f[3] = (short)f2bf(a.w);
            f[4] = (short)f2bf(bb.x); f[5] = (short)f2bf(bb.y);
            f[6] = (short)f2bf(bb.z); f[7] = (short)f2bf(bb.w);
            qf[qs][c] = f;
        }
    }

    // ---- online-softmax state; sink = virtual first key with value 0 ----
    const float sinkv = sinks[h];
    float m_i[2][4], l_i[2][4];
    float4v accO[2][8];
    for (int qs = 0; qs < 2; ++qs)
        for (int r = 0; r < 4; ++r) { m_i[qs][r] = sinkv; l_i[qs][r] = 1.0f; }
    for (int qs = 0; qs < 2; ++qs)
        for (int f = 0; f < 8; ++f) accO[qs][f] = (float4v)0.0f;

    int kt0 = q0 - WIN; if (kt0 < 0) kt0 = 0; kt0 &= ~31;
    const int kend = q0 + 32;

    for (int k0 = kt0; k0 < kend; k0 += 32) {
        __syncthreads();   // protect LDS K/V from previous iteration's readers
        // ---- cooperative stage: K tile (natural) + V tile (transposed), bf16 ----
        {
            const int row = tid >> 3;           // 0..31  (key within tile)
            const int col = (tid & 7) * 16;     // dim chunk
            const float* kr = kbase + (size_t)(k0 + row) * (NKVH * HD) + kvh * HD + col;
            unsigned int* kd = (unsigned int*)&Klds[row * 136 + col];
            for (int i = 0; i < 4; ++i) {
                float4 x = *(const float4*)(kr + i * 4);
                kd[i * 2 + 0] = (unsigned)f2bf(x.x) | ((unsigned)f2bf(x.y) << 16);
                kd[i * 2 + 1] = (unsigned)f2bf(x.z) | ((unsigned)f2bf(x.w) << 16);
            }
            const float* vr = vbase + (size_t)(k0 + row) * (NKVH * HD) + kvh * HD + col;
            for (int i = 0; i < 4; ++i) {
                float4 x = *(const float4*)(vr + i * 4);
                Vlds[(col + i * 4 + 0) * 40 + row] = f2bf(x.x);
                Vlds[(col + i * 4 + 1) * 40 + row] = f2bf(x.y);
                Vlds[(col + i * 4 + 2) * 40 + row] = f2bf(x.z);
                Vlds[(col + i * 4 + 3) * 40 + row] = f2bf(x.w);
            }
        }
        __syncthreads();

        // ---- S = Q K^T  (two 16x16 key sub-tiles per q sub-tile) ----
        float4v sacc[2][2];
        sacc[0][0] = (float4v)0.0f; sacc[0][1] = (float4v)0.0f;
        sacc[1][0] = (float4v)0.0f; sacc[1][1] = (float4v)0.0f;
        for (int ks = 0; ks < 2; ++ks) {
            for (int c = 0; c < 4; ++c) {
                short8 kf = *(const short8*)&Klds[(ks * 16 + l15) * 136 + c * 32 + quad * 8];
                sacc[0][ks] = __builtin_amdgcn_mfma_f32_16x16x32_bf16(qf[0][c], kf, sacc[0][ks], 0, 0, 0);
                sacc[1][ks] = __builtin_amdgcn_mfma_f32_16x16x32_bf16(qf[1][c], kf, sacc[1][ks], 0, 0, 0);
            }
        }

        // ---- masked online softmax (C layout: row = quad*4+r, col = l15 = key) ----
        for (int qs = 0; qs < 2; ++qs) {
            const int qbase_i = q0 + qs * 16 + quad * 4;
            float p[2][4];
            float tmax[4];
            for (int r = 0; r < 4; ++r) {
                const int qq = qbase_i + r;
                const int ka = k0 + l15, kb = k0 + 16 + l15;
                float s0 = sacc[qs][0][r] * QSCALE;
                float s1 = sacc[qs][1][r] * QSCALE;
                s0 = (ka <= qq && (qq - ka) <= WIN) ? s0 : -1e30f;
                s1 = (kb <= qq && (qq - kb) <= WIN) ? s1 : -1e30f;
                p[0][r] = s0; p[1][r] = s1;
                float mx = fmaxf(s0, s1);
                mx = fmaxf(mx, __shfl_xor(mx, 1));
                mx = fmaxf(mx, __shfl_xor(mx, 2));
                mx = fmaxf(mx, __shfl_xor(mx, 4));
                mx = fmaxf(mx, __shfl_xor(mx, 8));
                tmax[r] = mx;
            }
            unsigned short* P = Plds[wave];
            for (int r = 0; r < 4; ++r) {
                const float mold = m_i[qs][r];
                const float mnew = fmaxf(mold, tmax[r]);
                const float alpha = __expf(mold - mnew);
                m_i[qs][r] = mnew;
                const float p0 = __expf(p[0][r] - mnew);
                const float p1 = __expf(p[1][r] - mnew);
                float rs = p0 + p1;
                rs += __shfl_xor(rs, 1);
                rs += __shfl_xor(rs, 2);
                rs += __shfl_xor(rs, 4);
                rs += __shfl_xor(rs, 8);
                l_i[qs][r] = l_i[qs][r] * alpha + rs;
                for (int f = 0; f < 8; ++f) accO[qs][f][r] *= alpha;
                const int prow = (qs * 16 + quad * 4 + r) * 40;
                P[prow + l15]      = f2bf(p0);
                P[prow + 16 + l15] = f2bf(p1);
            }
        }
        __syncthreads();   // P: C-layout write -> A-layout read (cross-lane)

        // ---- O += P V ----
        short8 pf0 = *(const short8*)&Plds[wave][l15 * 40 + quad * 8];
        short8 pf1 = *(const short8*)&Plds[wave][(16 + l15) * 40 + quad * 8];
        for (int f = 0; f < 8; ++f) {
            short8 vf = *(const short8*)&Vlds[(f * 16 + l15) * 40 + quad * 8];
            accO[0][f] = __builtin_amdgcn_mfma_f32_16x16x32_bf16(pf0, vf, accO[0][f], 0, 0, 0);
            accO[1][f] = __builtin_amdgcn_mfma_f32_16x16x32_bf16(pf1, vf, accO[1][f], 0, 0, 0);
        }
    }

    // ---- epilogue: divide by softmax denom, store ----
    float* obase = og + (size_t)(b * SEQ) * (NH * HD);
    for (int qs = 0; qs < 2; ++qs) {
        for (int r = 0; r < 4; ++r) {
            const float inv = 1.0f / l_i[qs][r];
            const int row = q0 + qs * 16 + quad * 4 + r;
            float* orow = obase + (size_t)row * (NH * HD) + h * HD;
            for (int f = 0; f < 8; ++f)
                orow[f * 16 + l15] = accO[qs][f][r] * inv;
        }
    }
}

extern "C" void kernel_launch(void* const* d_in, const int* in_sizes, int n_in,
                              void* d_out, int out_size, void* d_ws, size_t ws_size,
                              hipStream_t stream) {
    const float* q     = (const float*)d_in[0];
    const float* k     = (const float*)d_in[1];
    const float* v     = (const float*)d_in[2];
    const float* sinks = (const float*)d_in[3];
    float* o = (float*)d_out;
    const int B = 4;
    dim3 grid(B * NKVH * (SEQ / 32));
    dim3 block(256);
    attn_swa_sink_kernel<<<grid, block, 0, stream>>>(q, k, v, sinks, o);
}

// Round 2
// 259.378 us; speedup vs baseline: 1.6352x; 1.6352x over previous
//
#include <hip/hip_runtime.h>
#include <hip/hip_bf16.h>

#define NH    16
#define NKVH  4
#define HD    128
#define WIN   1024
#define SEQ   2048
#define QROW  (NH * HD)    // 2048 floats per token row (q, o)
#define KROW  (NKVH * HD)  // 512 floats per token row (k, v)
#define LOG2E 1.4426950408889634f
#define QSC   (0.08838834764831845f * LOG2E)

#define KSTR 136   // Klds row stride in shorts (32 rows x 128 dims + 8 pad)
#define VSTR 36    // Vlds row stride in shorts (128 dim-rows x 32 keys + 4 pad)

typedef __attribute__((ext_vector_type(8))) short short8;
typedef __attribute__((ext_vector_type(4))) short short4v;
typedef __attribute__((ext_vector_type(4))) float float4v;

#if __has_builtin(__builtin_amdgcn_mfma_f32_16x16x16bf16_1k)
#define MFMA_PV(a, b, c) __builtin_amdgcn_mfma_f32_16x16x16bf16_1k(a, b, c, 0, 0, 0)
#elif __has_builtin(__builtin_amdgcn_mfma_f32_16x16x16_bf16)
#define MFMA_PV(a, b, c) __builtin_amdgcn_mfma_f32_16x16x16_bf16(a, b, c, 0, 0, 0)
#else
static __device__ __forceinline__ float4v mfma_pv_fallback(short4v a, short4v b, float4v c) {
    asm volatile("v_mfma_f32_16x16x16_bf16 %0, %1, %2, %0" : "+v"(c) : "v"(a), "v"(b));
    return c;
}
#define MFMA_PV(a, b, c) mfma_pv_fallback(a, b, c)
#endif

__device__ __forceinline__ unsigned int pk2bf(float a, float b) {
    float2 t; t.x = a; t.y = b;
    __hip_bfloat162 h = __float22bfloat162_rn(t);
    union { __hip_bfloat162 h; unsigned int u; } cv;
    cv.h = h;
    return cv.u;
}

// block = 256 threads = 4 waves; wave w = head kvh*4+w, 32 queries.
// S^T = K*Q^T formulation: probs land in C-layout == A-layout of 16x16x16 PV mfma.
__global__ __launch_bounds__(256, 2)
void attn_swa_sink_kernel(const float* __restrict__ qg, const float* __restrict__ kg,
                          const float* __restrict__ vg, const float* __restrict__ sinks,
                          float* __restrict__ og) {
    __shared__ __align__(16) unsigned short Klds[32 * KSTR];   // [key][dim] bf16
    __shared__ __align__(16) unsigned short Vlds[128 * VSTR];  // [dim][key] bf16 (V^T)

    // XCD swizzle: all 64 q-tiles of one (b,kvh) land on one XCD (gid%8 heuristic)
    const int gid  = blockIdx.x;
    const int xcd  = gid & 7;
    const int rest = gid >> 3;
    const int qt   = rest >> 1;
    const int g    = ((rest & 1) << 3) | xcd;   // 0..15 = (b,kvh)
    const int b    = g >> 2;
    const int kvh  = g & 3;

    const int tid  = threadIdx.x;
    const int wave = tid >> 6;
    const int lane = tid & 63;
    const int l15  = lane & 15;
    const int quad = lane >> 4;
    const int h    = kvh * 4 + wave;
    const int q0   = qt * 32;

    const float* qbase = qg + (size_t)(b * SEQ) * QROW;
    const float* kbase = kg + (size_t)(b * SEQ) * KROW + kvh * HD;
    const float* vbase = vg + (size_t)(b * SEQ) * KROW + kvh * HD;

    // ---- Q fragments (B-operand of K*Q^T): col=query=l15, k=dim=quad*8+j (+32c) ----
    // scale*log2e folded in: softmax runs in exp2 domain
    short8 qf[2][4];
#pragma unroll
    for (int qs = 0; qs < 2; ++qs) {
        const float* qr = qbase + (size_t)(q0 + qs * 16 + l15) * QROW + h * HD + quad * 8;
#pragma unroll
        for (int c = 0; c < 4; ++c) {
            float4 x = *(const float4*)(qr + c * 32);
            float4 y = *(const float4*)(qr + c * 32 + 4);
            union { unsigned int u[4]; short8 s; } cv;
            cv.u[0] = pk2bf(x.x * QSC, x.y * QSC);
            cv.u[1] = pk2bf(x.z * QSC, x.w * QSC);
            cv.u[2] = pk2bf(y.x * QSC, y.y * QSC);
            cv.u[3] = pk2bf(y.z * QSC, y.w * QSC);
            qf[qs][c] = cv.s;
        }
    }

    const float sinkv = sinks[h] * LOG2E;   // sink logit, log2 domain
    float m_i[2] = { sinkv, sinkv };
    float l_i[2] = { 1.0f, 1.0f };
    float4v accO[2][8];                      // O C-layout: row=query=quad*4+r, col=dim=f*16+l15
#pragma unroll
    for (int qs = 0; qs < 2; ++qs)
#pragma unroll
        for (int f = 0; f < 8; ++f) accO[qs][f] = (float4v)0.0f;

    // staging thread mapping
    const int krow = tid >> 3, kcg = tid & 7;    // K: one key row, dims kcg*16..+15
    const int vkg  = tid >> 5, vdg = tid & 31;   // V: keys vkg*4..+3, dims vdg*4..+3

    int kt0 = q0 - WIN; if (kt0 < 0) kt0 = 0;
    const int kend = q0 + 32;

    // ---- prefetch first tile into registers ----
    float4 kreg[4], vreg[4];
    {
        const float* kr = kbase + (size_t)(kt0 + krow) * KROW + kcg * 16;
        kreg[0] = *(const float4*)(kr + 0);
        kreg[1] = *(const float4*)(kr + 4);
        kreg[2] = *(const float4*)(kr + 8);
        kreg[3] = *(const float4*)(kr + 12);
        const float* vr = vbase + (size_t)(kt0 + vkg * 4) * KROW + vdg * 4;
        vreg[0] = *(const float4*)(vr + 0 * KROW);
        vreg[1] = *(const float4*)(vr + 1 * KROW);
        vreg[2] = *(const float4*)(vr + 2 * KROW);
        vreg[3] = *(const float4*)(vr + 3 * KROW);
    }

    for (int k0 = kt0; k0 < kend; k0 += 32) {
        __syncthreads();   // all waves done reading previous LDS tile
        // ---- convert + write staged tile (bf16), b64 stores ----
        {
            uint2* kd = (uint2*)&Klds[krow * KSTR + kcg * 16];
#pragma unroll
            for (int i = 0; i < 4; ++i) {
                uint2 w;
                w.x = pk2bf(((const float*)&kreg[i])[0], ((const float*)&kreg[i])[1]);
                w.y = pk2bf(((const float*)&kreg[i])[2], ((const float*)&kreg[i])[3]);
                kd[i] = w;
            }
#pragma unroll
            for (int i = 0; i < 4; ++i) {   // transpose 4 keys x 4 dims
                uint2 w;
                w.x = pk2bf(((const float*)&vreg[0])[i], ((const float*)&vreg[1])[i]);
                w.y = pk2bf(((const float*)&vreg[2])[i], ((const float*)&vreg[3])[i]);
                *(uint2*)&Vlds[(vdg * 4 + i) * VSTR + vkg * 4] = w;
            }
        }
        // ---- issue prefetch for next tile (latency hidden behind compute) ----
        if (k0 + 32 < kend) {
            const float* kr = kbase + (size_t)(k0 + 32 + krow) * KROW + kcg * 16;
            kreg[0] = *(const float4*)(kr + 0);
            kreg[1] = *(const float4*)(kr + 4);
            kreg[2] = *(const float4*)(kr + 8);
            kreg[3] = *(const float4*)(kr + 12);
            const float* vr = vbase + (size_t)(k0 + 32 + vkg * 4) * KROW + vdg * 4;
            vreg[0] = *(const float4*)(vr + 0 * KROW);
            vreg[1] = *(const float4*)(vr + 1 * KROW);
            vreg[2] = *(const float4*)(vr + 2 * KROW);
            vreg[3] = *(const float4*)(vr + 3 * KROW);
        }
        __syncthreads();   // LDS tile ready

        // ---- S^T = K * Q^T : C row = key = quad*4+r, col = query = l15 ----
        float4v sacc[2][2]; // [ks][qs]
        sacc[0][0] = (float4v)0.0f; sacc[0][1] = (float4v)0.0f;
        sacc[1][0] = (float4v)0.0f; sacc[1][1] = (float4v)0.0f;
#pragma unroll
        for (int c = 0; c < 4; ++c) {
            short8 kf0 = *(const short8*)&Klds[(l15)      * KSTR + c * 32 + quad * 8];
            short8 kf1 = *(const short8*)&Klds[(16 + l15) * KSTR + c * 32 + quad * 8];
            sacc[0][0] = __builtin_amdgcn_mfma_f32_16x16x32_bf16(kf0, qf[0][c], sacc[0][0], 0, 0, 0);
            sacc[0][1] = __builtin_amdgcn_mfma_f32_16x16x32_bf16(kf0, qf[1][c], sacc[0][1], 0, 0, 0);
            sacc[1][0] = __builtin_amdgcn_mfma_f32_16x16x32_bf16(kf1, qf[0][c], sacc[1][0], 0, 0, 0);
            sacc[1][1] = __builtin_amdgcn_mfma_f32_16x16x32_bf16(kf1, qf[1][c], sacc[1][1], 0, 0, 0);
        }

        // ---- online softmax in S^T domain (per-query state lives at lane l15) ----
        short4v pf[2][2]; // [qs][ks] : P as A-operand of 16x16x16, k = quad*4+j == r
#pragma unroll
        for (int qs = 0; qs < 2; ++qs) {
            const int query = q0 + qs * 16 + l15;
            const bool full = (k0 + 31 <= q0 + qs * 16) && (q0 + qs * 16 + 15 - k0 <= WIN);
            float ps[2][4];
            float mx = -3.0e38f;
            if (full) {
#pragma unroll
                for (int ks = 0; ks < 2; ++ks)
#pragma unroll
                    for (int r = 0; r < 4; ++r) {
                        float s = sacc[ks][qs][r];
                        ps[ks][r] = s;
                        mx = fmaxf(mx, s);
                    }
            } else {
#pragma unroll
                for (int ks = 0; ks < 2; ++ks)
#pragma unroll
                    for (int r = 0; r < 4; ++r) {
                        const int key = k0 + ks * 16 + quad * 4 + r;
                        const unsigned d = (unsigned)(query - key);
                        float s = (d <= WIN) ? sacc[ks][qs][r] : -1.0e30f;
                        ps[ks][r] = s;
                        mx = fmaxf(mx, s);
                    }
            }
            mx = fmaxf(mx, __shfl_xor(mx, 16));
            mx = fmaxf(mx, __shfl_xor(mx, 32));
            const float mold  = m_i[qs];
            const float mnew  = fmaxf(mold, mx);
            const float alpha = exp2f(mold - mnew);
            m_i[qs] = mnew;
            float sum = 0.0f;
#pragma unroll
            for (int ks = 0; ks < 2; ++ks) {
                float p0 = exp2f(ps[ks][0] - mnew);
                float p1 = exp2f(ps[ks][1] - mnew);
                float p2 = exp2f(ps[ks][2] - mnew);
                float p3 = exp2f(ps[ks][3] - mnew);
                sum += (p0 + p1) + (p2 + p3);
                union { unsigned int u[2]; short4v s; } cv;
                cv.u[0] = pk2bf(p0, p1);
                cv.u[1] = pk2bf(p2, p3);
                pf[qs][ks] = cv.s;
            }
            sum += __shfl_xor(sum, 16);
            sum += __shfl_xor(sum, 32);
            l_i[qs] = l_i[qs] * alpha + sum;
            // broadcast alpha from query-domain (l15) to O-row domain (quad*4+r)
#pragma unroll
            for (int r = 0; r < 4; ++r) {
                const float ar = __shfl(alpha, quad * 4 + r);
#pragma unroll
                for (int f = 0; f < 8; ++f) accO[qs][f][r] *= ar;
            }
        }

        // ---- O += P*V : A = pf (in-register), B = V^T b64 reads ----
#pragma unroll
        for (int f = 0; f < 8; ++f) {
#pragma unroll
            for (int ks = 0; ks < 2; ++ks) {
                short4v vf = *(const short4v*)&Vlds[(f * 16 + l15) * VSTR + ks * 16 + quad * 4];
                accO[0][f] = MFMA_PV(pf[0][ks], vf, accO[0][f]);
                accO[1][f] = MFMA_PV(pf[1][ks], vf, accO[1][f]);
            }
        }
    }

    // ---- epilogue ----
    float* obase = og + (size_t)(b * SEQ) * QROW + h * HD;
#pragma unroll
    for (int qs = 0; qs < 2; ++qs) {
#pragma unroll
        for (int r = 0; r < 4; ++r) {
            const float lq  = __shfl(l_i[qs], quad * 4 + r);
            const float inv = __builtin_amdgcn_rcpf(lq);
            float* orow = obase + (size_t)(q0 + qs * 16 + quad * 4 + r) * QROW;
#pragma unroll
            for (int f = 0; f < 8; ++f)
                orow[f * 16 + l15] = accO[qs][f][r] * inv;
        }
    }
}

extern "C" void kernel_launch(void* const* d_in, const int* in_sizes, int n_in,
                              void* d_out, int out_size, void* d_ws, size_t ws_size,
                              hipStream_t stream) {
    const float* q     = (const float*)d_in[0];
    const float* k     = (const float*)d_in[1];
    const float* v     = (const float*)d_in[2];
    const float* sinks = (const float*)d_in[3];
    float* o = (float*)d_out;
    const int B = 4;
    dim3 grid(B * NKVH * (SEQ / 32));
    dim3 block(256);
    attn_swa_sink_kernel<<<grid, block, 0, stream>>>(q, k, v, sinks, o);
}

// Round 3
// 244.345 us; speedup vs baseline: 1.7358x; 1.0615x over previous
//
#include <hip/hip_runtime.h>
#include <hip/hip_bf16.h>

#define NH    16
#define NKVH  4
#define HD    128
#define WIN   1024
#define SEQ   2048
#define NB    4
#define QROW  (NH * HD)    // 2048 floats per token row (q, o)
#define KROW  (NKVH * HD)  // 512 elems per token row (k, v)
#define LOG2E 1.4426950408889634f
#define QSC   (0.08838834764831845f * LOG2E)

#define KSTR 136   // Klds row stride in shorts (17x16B, 2-way max on A-frag reads)
#define VSTR 40    // Vlds row stride in shorts (5x16B)

typedef __attribute__((ext_vector_type(8))) short short8;
typedef __attribute__((ext_vector_type(4))) float float4v;

__device__ __forceinline__ unsigned short f2bf(float f) {
    unsigned int u = __float_as_uint(f);
    unsigned int r = (u + 0x7FFFu + ((u >> 16) & 1u)) >> 16;
    return (unsigned short)r;
}

__device__ __forceinline__ unsigned int pk2bf(float a, float b) {
    float2 t; t.x = a; t.y = b;
    __hip_bfloat162 h = __float22bfloat162_rn(t);
    union { __hip_bfloat162 h; unsigned int u; } cv;
    cv.h = h;
    return cv.u;
}

// ---- pre-pass 1: K fp32 -> bf16, layout preserved [token][kvh*128+d] ----
__global__ __launch_bounds__(256)
void cvt_k_kernel(const float* __restrict__ kg, unsigned short* __restrict__ kb) {
    const size_t idx = ((size_t)blockIdx.x * 256 + threadIdx.x) * 8;
    float4 a = *(const float4*)(kg + idx);
    float4 b = *(const float4*)(kg + idx + 4);
    uint4 w;
    w.x = pk2bf(a.x, a.y); w.y = pk2bf(a.z, a.w);
    w.z = pk2bf(b.x, b.y); w.w = pk2bf(b.z, b.w);
    *(uint4*)(kb + idx) = w;
}

// ---- pre-pass 2: V fp32 [token][kvh*128+d] -> V^T bf16 [b][kvh][d][seq] ----
#define VTSTR 72
__global__ __launch_bounds__(256)
void cvt_vt_kernel(const float* __restrict__ vg, unsigned short* __restrict__ vt) {
    __shared__ unsigned short T[128 * VTSTR];
    const int blk = blockIdx.x;          // 512 = b(4) x kvh(4) x kb(32)
    const int b   = blk >> 7;
    const int kvh = (blk >> 5) & 3;
    const int kb  = blk & 31;
    const int t   = threadIdx.x;

    // read: 64 keys x 128 dims fp32, coalesced; scatter-transpose into LDS
    const int klocal = t >> 2;
    const int d0     = (t & 3) * 32;
    const float* src = vg + (size_t)(b * SEQ + kb * 64 + klocal) * KROW + kvh * HD + d0;
#pragma unroll
    for (int c = 0; c < 8; ++c) {
        float4 x = *(const float4*)(src + c * 4);
        T[(d0 + c * 4 + 0) * VTSTR + klocal] = f2bf(x.x);
        T[(d0 + c * 4 + 1) * VTSTR + klocal] = f2bf(x.y);
        T[(d0 + c * 4 + 2) * VTSTR + klocal] = f2bf(x.z);
        T[(d0 + c * 4 + 3) * VTSTR + klocal] = f2bf(x.w);
    }
    __syncthreads();

    // write: dim-major rows, 64B per thread contiguous
    const int d    = t >> 1;
    const int half = t & 1;
    const unsigned short* s = &T[d * VTSTR + half * 32];
    unsigned short* dst = vt + ((size_t)((b * NKVH + kvh) * HD) + d) * SEQ + kb * 64 + half * 32;
#pragma unroll
    for (int c = 0; c < 4; ++c)
        *(uint4*)(dst + c * 8) = *(const uint4*)(s + c * 8);
}

// block = 256 threads = 4 waves; wave w = head kvh*4+w, 32 queries.
// S^T = K*Q^T with INTERLEAVED key tiles (even keys rows 0-15, odd rows 16-31):
// probs pack directly into the A-layout of 16x16x32 PV mfma (k = quad*8+j = key).
__global__ __launch_bounds__(256, 3)
void attn_swa_sink_kernel(const float* __restrict__ qg,
                          const unsigned short* __restrict__ kb,
                          const unsigned short* __restrict__ vt,
                          const float* __restrict__ sinks,
                          float* __restrict__ og) {
    __shared__ __align__(16) unsigned short Klds[32 * KSTR];   // [interleaved key][dim] bf16
    __shared__ __align__(16) unsigned short Vlds[128 * VSTR];  // [dim][key] bf16 (V^T)

    // XCD swizzle: q-tiles of one (b,kvh) stay on one XCD
    const int gid  = blockIdx.x;
    const int xcd  = gid & 7;
    const int rest = gid >> 3;
    const int qt   = rest >> 1;
    const int g    = ((rest & 1) << 3) | xcd;
    const int b    = g >> 2;
    const int kvh  = g & 3;

    const int tid  = threadIdx.x;
    const int wave = tid >> 6;
    const int lane = tid & 63;
    const int l15  = lane & 15;
    const int quad = lane >> 4;
    const int h    = kvh * 4 + wave;
    const int q0   = qt * 32;

    const float* qbase = qg + (size_t)(b * SEQ) * QROW;
    const unsigned short* kbase = kb + (size_t)(b * SEQ) * KROW + kvh * HD;
    const unsigned short* vtbase = vt + (size_t)((b * NKVH + kvh) * HD) * SEQ;

    // ---- Q fragments (B-operand of K*Q^T): col=query=l15, k=dim=quad*8+j (+32c) ----
    short8 qf[2][4];
#pragma unroll
    for (int qs = 0; qs < 2; ++qs) {
        const float* qr = qbase + (size_t)(q0 + qs * 16 + l15) * QROW + h * HD + quad * 8;
#pragma unroll
        for (int c = 0; c < 4; ++c) {
            float4 x = *(const float4*)(qr + c * 32);
            float4 y = *(const float4*)(qr + c * 32 + 4);
            union { unsigned int u[4]; short8 s; } cv;
            cv.u[0] = pk2bf(x.x * QSC, x.y * QSC);
            cv.u[1] = pk2bf(x.z * QSC, x.w * QSC);
            cv.u[2] = pk2bf(y.x * QSC, y.y * QSC);
            cv.u[3] = pk2bf(y.z * QSC, y.w * QSC);
            qf[qs][c] = cv.s;
        }
    }

    const float sinkv = sinks[h] * LOG2E;
    float m_i[2] = { sinkv, sinkv };
    float l_i[2] = { 1.0f, 1.0f };
    float4v accO[2][8];   // row=query=quad*4+r, col=dim=f*16+l15
#pragma unroll
    for (int qs = 0; qs < 2; ++qs)
#pragma unroll
        for (int f = 0; f < 8; ++f) accO[qs][f] = (float4v)0.0f;

    // staging thread mapping (bf16 sources, no conversion in loop)
    const int kr  = tid >> 3, kcg = tid & 7;     // K: key row kr, dims kcg*16..+15
    const int lrow = ((kr & 1) << 4) | (kr >> 1);  // interleaved LDS row
    const int vd  = tid >> 1, vh = tid & 1;      // V^T: dim row vd, key half vh*16

    int kt0 = q0 - WIN; if (kt0 < 0) kt0 = 0;
    const int kend = q0 + 32;

    uint4 kpre0, kpre1, vpre0, vpre1;
    {
        const unsigned short* kp = kbase + (size_t)(kt0 + kr) * KROW + kcg * 16;
        kpre0 = *(const uint4*)(kp);
        kpre1 = *(const uint4*)(kp + 8);
        const unsigned short* vp = vtbase + (size_t)vd * SEQ + kt0 + vh * 16;
        vpre0 = *(const uint4*)(vp);
        vpre1 = *(const uint4*)(vp + 8);
    }

    for (int k0 = kt0; k0 < kend; k0 += 32) {
        __syncthreads();
        // ---- commit staged tile (pure b128 writes) ----
        *(uint4*)&Klds[lrow * KSTR + kcg * 16]     = kpre0;
        *(uint4*)&Klds[lrow * KSTR + kcg * 16 + 8] = kpre1;
        *(uint4*)&Vlds[vd * VSTR + vh * 16]        = vpre0;
        *(uint4*)&Vlds[vd * VSTR + vh * 16 + 8]    = vpre1;
        // ---- prefetch next tile ----
        if (k0 + 32 < kend) {
            const unsigned short* kp = kbase + (size_t)(k0 + 32 + kr) * KROW + kcg * 16;
            kpre0 = *(const uint4*)(kp);
            kpre1 = *(const uint4*)(kp + 8);
            const unsigned short* vp = vtbase + (size_t)vd * SEQ + (k0 + 32) + vh * 16;
            vpre0 = *(const uint4*)(vp);
            vpre1 = *(const uint4*)(vp + 8);
        }
        __syncthreads();

        // ---- S^T = K * Q^T : C row = interleaved key, col = query = l15 ----
        float4v sacc[2][2]; // [ks(parity)][qs]
        sacc[0][0] = (float4v)0.0f; sacc[0][1] = (float4v)0.0f;
        sacc[1][0] = (float4v)0.0f; sacc[1][1] = (float4v)0.0f;
#pragma unroll
        for (int c = 0; c < 4; ++c) {
            short8 kf0 = *(const short8*)&Klds[(l15)      * KSTR + c * 32 + quad * 8];
            short8 kf1 = *(const short8*)&Klds[(16 + l15) * KSTR + c * 32 + quad * 8];
            sacc[0][0] = __builtin_amdgcn_mfma_f32_16x16x32_bf16(kf0, qf[0][c], sacc[0][0], 0, 0, 0);
            sacc[0][1] = __builtin_amdgcn_mfma_f32_16x16x32_bf16(kf0, qf[1][c], sacc[0][1], 0, 0, 0);
            sacc[1][0] = __builtin_amdgcn_mfma_f32_16x16x32_bf16(kf1, qf[0][c], sacc[1][0], 0, 0, 0);
            sacc[1][1] = __builtin_amdgcn_mfma_f32_16x16x32_bf16(kf1, qf[1][c], sacc[1][1], 0, 0, 0);
        }

        // ---- online softmax; P packs into x32 A-layout (key = k0 + 8*quad + 2r + ks) ----
        short8 pf[2];
#pragma unroll
        for (int qs = 0; qs < 2; ++qs) {
            const int query = q0 + qs * 16 + l15;
            const bool full = (k0 + 31 <= q0 + qs * 16) && (q0 + qs * 16 + 15 - k0 <= WIN);
            float ps[2][4];
            float mx = -3.0e38f;
            if (full) {
#pragma unroll
                for (int ks = 0; ks < 2; ++ks)
#pragma unroll
                    for (int r = 0; r < 4; ++r) {
                        float s = sacc[ks][qs][r];
                        ps[ks][r] = s;
                        mx = fmaxf(mx, s);
                    }
            } else {
#pragma unroll
                for (int ks = 0; ks < 2; ++ks)
#pragma unroll
                    for (int r = 0; r < 4; ++r) {
                        const int key = k0 + 8 * quad + 2 * r + ks;
                        const unsigned d = (unsigned)(query - key);
                        float s = (d <= WIN) ? sacc[ks][qs][r] : -1.0e30f;
                        ps[ks][r] = s;
                        mx = fmaxf(mx, s);
                    }
            }
            mx = fmaxf(mx, __shfl_xor(mx, 16));
            mx = fmaxf(mx, __shfl_xor(mx, 32));
            const float mold = m_i[qs];
            const float mnew = fmaxf(mold, mx);
            m_i[qs] = mnew;
            float sum = 0.0f;
            union { unsigned int u[4]; short8 s; } cv;
#pragma unroll
            for (int r = 0; r < 4; ++r) {
                const float p0 = exp2f(ps[0][r] - mnew);
                const float p1 = exp2f(ps[1][r] - mnew);
                sum += p0 + p1;
                cv.u[r] = pk2bf(p0, p1);
            }
            pf[qs] = cv.s;
            sum += __shfl_xor(sum, 16);
            sum += __shfl_xor(sum, 32);
            if (__any(mnew > mold)) {
                const float alpha = exp2f(mold - mnew);
                l_i[qs] = l_i[qs] * alpha + sum;
#pragma unroll
                for (int r = 0; r < 4; ++r) {
                    const float ar = __shfl(alpha, quad * 4 + r);
#pragma unroll
                    for (int f = 0; f < 8; ++f) accO[qs][f][r] *= ar;
                }
            } else {
                l_i[qs] += sum;
            }
        }

        // ---- O += P*V via 16x16x32 (B-frag = contiguous b128 from V^T) ----
#pragma unroll
        for (int f = 0; f < 8; ++f) {
            short8 vf = *(const short8*)&Vlds[(f * 16 + l15) * VSTR + quad * 8];
            accO[0][f] = __builtin_amdgcn_mfma_f32_16x16x32_bf16(pf[0], vf, accO[0][f], 0, 0, 0);
            accO[1][f] = __builtin_amdgcn_mfma_f32_16x16x32_bf16(pf[1], vf, accO[1][f], 0, 0, 0);
        }
    }

    // ---- epilogue ----
    float* obase = og + (size_t)(b * SEQ) * QROW + h * HD;
#pragma unroll
    for (int qs = 0; qs < 2; ++qs) {
#pragma unroll
        for (int r = 0; r < 4; ++r) {
            const float lq  = __shfl(l_i[qs], quad * 4 + r);
            const float inv = __builtin_amdgcn_rcpf(lq);
            float* orow = obase + (size_t)(q0 + qs * 16 + quad * 4 + r) * QROW;
#pragma unroll
            for (int f = 0; f < 8; ++f)
                orow[f * 16 + l15] = accO[qs][f][r] * inv;
        }
    }
}

extern "C" void kernel_launch(void* const* d_in, const int* in_sizes, int n_in,
                              void* d_out, int out_size, void* d_ws, size_t ws_size,
                              hipStream_t stream) {
    const float* q     = (const float*)d_in[0];
    const float* k     = (const float*)d_in[1];
    const float* v     = (const float*)d_in[2];
    const float* sinks = (const float*)d_in[3];
    float* o = (float*)d_out;

    unsigned short* kb = (unsigned short*)d_ws;                      // 8 MB
    unsigned short* vt = kb + (size_t)NB * SEQ * KROW;               // 8 MB

    // pre-pass: K -> bf16 (4M elems / 8 per thread / 256)
    cvt_k_kernel<<<dim3(NB * SEQ * KROW / (256 * 8)), dim3(256), 0, stream>>>(k, kb);
    // pre-pass: V -> V^T bf16 tiles
    cvt_vt_kernel<<<dim3(NB * NKVH * (SEQ / 64)), dim3(256), 0, stream>>>(v, vt);

    attn_swa_sink_kernel<<<dim3(NB * NKVH * (SEQ / 32)), dim3(256), 0, stream>>>(
        q, kb, vt, sinks, o);
}